// Round 2
// baseline (92.799 us; speedup 1.0000x reference)
//
#include <hip/hip_runtime.h>

// B=64, D=2048, UNITS=1024, NW=64; L = in_sizes[3]/(UNITS*NW) (~56).
//
// out[b,u] = sum_i x[b,i] * W[u,i] + bias[u], W[u,i] = w[k] where bucket k of
// unit u contains position i (indices 1-shifted, 0 = pad). Buckets PARTITION
// positions per unit -> every W[u,i] is written exactly once by the scatter
// (no zero-init needed), race-free.
//
// R11: two-kernel restructure through the workspace (ws ~256MB confirmed by
// the 268MB poison fills in the R10 profile).
//   Kernel A (build_W): scatter-materialize W[1024][2048] fp32 (8MB) in d_ws.
//     One wave per (u,k) bucket: coalesced idx loads, wave-uniform w[k],
//     scattered 4B global writes (L2-absorbed; W < L2 aggregate).
//   Kernel B (gemm_part): dense skinny GEMM. Replaces zero+LDS-scatter with a
//     contiguous 64KB W->LDS float4 copy; phase 2/3 identical to R9.
// Removes: duplicate index fetch+scatter (B_SPLIT=2 did everything twice),
// LDS zeroing, scatter bank conflicts, and per-CU phase serialization
// (memory-only kernel A overlaps across its own 16K blocks; B streams).
//
// R10 post-mortem: kernel absent from top-5 dispatches (all 41us poison
// fills) => kernel < 41us; dur_us 80.1 ~= fill(41) + kernel(~39). Composed
// floor for R11: A ~3-5us + B ~6-8us. Prediction: dur_us -> ~50-55 if the
// fill floor is in the timed region, ~10-15 if not.

#define B_DIM   64
#define D_DIM   2048
#define D4      (D_DIM / 4)     // 512 float4 per row
#define UNITS_N 1024
#define NW_N    64
#define U_PER_BLOCK 8
#define B_SPLIT 2
#define B_PER_BLOCK (B_DIM / B_SPLIT)               // 32
#define THREADS 1024
#define WAVES   (THREADS / 64)                      // 16
#define PAIRS_PER_WAVE (U_PER_BLOCK * NW_N / WAVES) // 32 (fallback only)
#define ROWS_PER_WAVE  (B_PER_BLOCK / WAVES)        // 2
#define STEPS   (D4 / 64)                           // 8

// ---------------- Kernel A: scatter-build W ----------------
// One wave per (u,k) bucket. 16384 blocks x 256 thr (4 waves).
__global__ __launch_bounds__(256)
void EfficientHashedLinear_72043781423546_buildW(
    const float* __restrict__ w,        // (64,)
    const int*   __restrict__ indices,  // (UNITS, NW, L) int32
    float*       __restrict__ W,        // (UNITS, D) workspace
    int L)
{
    const int bucket = blockIdx.x * 4 + (threadIdx.x >> 6);  // u*64 + k
    const int lane   = threadIdx.x & 63;
    const int u      = bucket >> 6;
    const int k      = bucket & 63;
    const float wk   = w[k];                                  // wave-uniform
    const int* bp    = indices + (size_t)bucket * L;
    for (int l = lane; l < L; l += 64) {
        const int idx = bp[l];                                // coalesced
        if (idx > 0) W[(size_t)u * D_DIM + idx - 1] = wk;     // scattered, unique
    }
}

// ---------------- Kernel B: dense skinny GEMM ----------------
// Grid (128,2) x 1024 thr. LDS 64KB: 8 contiguous W rows.
__global__ __launch_bounds__(THREADS)
void EfficientHashedLinear_72043781423546_gemm(
    const float* __restrict__ x,        // (64, 2048)
    const float* __restrict__ W,        // (UNITS, D)
    const float* __restrict__ bias,     // (1024,)
    float*       __restrict__ out)      // (64, 1024)
{
    __shared__ float rows[U_PER_BLOCK][D_DIM];   // 64 KB

    const int tid  = threadIdx.x;
    const int wave = tid >> 6;          // 0..15
    const int lane = tid & 63;
    const int u0   = blockIdx.x * U_PER_BLOCK;
    const int bh   = blockIdx.y;        // batch half: 0 or 1

    // Stage 8 W rows (64KB contiguous) into LDS, float4-coalesced.
    {
        const float4* g4 = (const float4*)(W + (size_t)u0 * D_DIM);
        float4* r4 = (float4*)rows;
        #pragma unroll
        for (int i = tid; i < U_PER_BLOCK * D4; i += THREADS)
            r4[i] = g4[i];
    }
    __syncthreads();

    // Phase 2: wave owns 2 batch rows (of this half's 32) x 8 units.
    const int b0 = bh * B_PER_BLOCK + wave * ROWS_PER_WAVE;
    const float4* x4 = (const float4*)x;

    float acc[ROWS_PER_WAVE][U_PER_BLOCK];
    #pragma unroll
    for (int bj = 0; bj < ROWS_PER_WAVE; ++bj)
        #pragma unroll
        for (int uu = 0; uu < U_PER_BLOCK; ++uu)
            acc[bj][uu] = 0.0f;

    #pragma unroll 1   // keep live set small; big unrolls spill (R2/R5)
    for (int step = 0; step < STEPS; ++step) {
        const int i4 = step * 64 + lane;          // 0..511
        float4 xv[ROWS_PER_WAVE];
        #pragma unroll
        for (int bj = 0; bj < ROWS_PER_WAVE; ++bj)
            xv[bj] = x4[(b0 + bj) * D4 + i4];     // 2 loads, one round trip
        #pragma unroll
        for (int uu = 0; uu < U_PER_BLOCK; ++uu) {
            const float4 rv = ((const float4*)rows[uu])[i4];   // ds_read_b128
            #pragma unroll
            for (int bj = 0; bj < ROWS_PER_WAVE; ++bj) {
                acc[bj][uu] += xv[bj].x * rv.x;
                acc[bj][uu] += xv[bj].y * rv.y;
                acc[bj][uu] += xv[bj].z * rv.z;
                acc[bj][uu] += xv[bj].w * rv.w;
            }
        }
    }

    // Phase 3: butterfly reduce, add bias, store (16 outputs/wave).
    #pragma unroll
    for (int bj = 0; bj < ROWS_PER_WAVE; ++bj) {
        #pragma unroll
        for (int uu = 0; uu < U_PER_BLOCK; ++uu) {
            float v = acc[bj][uu];
            #pragma unroll
            for (int off = 32; off > 0; off >>= 1)
                v += __shfl_down(v, off, 64);
            if (lane == 0)
                out[(b0 + bj) * UNITS_N + (u0 + uu)] = v + bias[u0 + uu];
        }
    }
}

// ---------------- Fallback: R9 monolithic (if ws too small) ----------------
__global__ __launch_bounds__(THREADS)
void EfficientHashedLinear_72043781423546_kernel(
    const float* __restrict__ x,
    const float* __restrict__ w,
    const float* __restrict__ bias,
    const int*   __restrict__ indices,
    float*       __restrict__ out,
    int L)
{
    __shared__ float rows[U_PER_BLOCK][D_DIM];
    __shared__ float w_lds[NW_N];

    const int tid  = threadIdx.x;
    const int wave = tid >> 6;
    const int lane = tid & 63;
    const int u0   = blockIdx.x * U_PER_BLOCK;
    const int bh   = blockIdx.y;

    {
        float4* r4 = (float4*)rows;
        const float4 z = make_float4(0.f, 0.f, 0.f, 0.f);
        #pragma unroll
        for (int i = tid; i < U_PER_BLOCK * D4; i += THREADS)
            r4[i] = z;
        if (tid < NW_N) w_lds[tid] = w[tid];
    }

    int idxv[PAIRS_PER_WAVE];
    #pragma unroll
    for (int p = 0; p < PAIRS_PER_WAVE; ++p) {
        const int pair = wave * PAIRS_PER_WAVE + p;
        const int uu   = pair >> 6;
        const int k    = pair & 63;
        const int* bp  = indices + ((size_t)(u0 + uu) * NW_N + k) * L;
        idxv[p] = (lane < L) ? bp[lane] : 0;
    }

    __syncthreads();

    #pragma unroll
    for (int p = 0; p < PAIRS_PER_WAVE; ++p) {
        const int pair = wave * PAIRS_PER_WAVE + p;
        const int uu   = pair >> 6;
        const int k    = pair & 63;
        if (idxv[p] > 0) rows[uu][idxv[p] - 1] = w_lds[k];
    }
    if (L > 64) {
        #pragma unroll 1
        for (int p = 0; p < PAIRS_PER_WAVE; ++p) {
            const int pair = wave * PAIRS_PER_WAVE + p;
            const int uu   = pair >> 6;
            const int k    = pair & 63;
            const int* bp  = indices + ((size_t)(u0 + uu) * NW_N + k) * L;
            const float wk = w_lds[k];
            for (int l = 64 + lane; l < L; l += 64) {
                int idx = bp[l];
                if (idx > 0) rows[uu][idx - 1] = wk;
            }
        }
    }
    __syncthreads();

    const int b0 = bh * B_PER_BLOCK + wave * ROWS_PER_WAVE;
    const float4* x4 = (const float4*)x;

    float acc[ROWS_PER_WAVE][U_PER_BLOCK];
    #pragma unroll
    for (int bj = 0; bj < ROWS_PER_WAVE; ++bj)
        #pragma unroll
        for (int uu = 0; uu < U_PER_BLOCK; ++uu)
            acc[bj][uu] = 0.0f;

    #pragma unroll 1
    for (int step = 0; step < STEPS; ++step) {
        const int i4 = step * 64 + lane;
        float4 xv[ROWS_PER_WAVE];
        #pragma unroll
        for (int bj = 0; bj < ROWS_PER_WAVE; ++bj)
            xv[bj] = x4[(b0 + bj) * D4 + i4];
        #pragma unroll
        for (int uu = 0; uu < U_PER_BLOCK; ++uu) {
            const float4 rv = ((const float4*)rows[uu])[i4];
            #pragma unroll
            for (int bj = 0; bj < ROWS_PER_WAVE; ++bj) {
                acc[bj][uu] += xv[bj].x * rv.x;
                acc[bj][uu] += xv[bj].y * rv.y;
                acc[bj][uu] += xv[bj].z * rv.z;
                acc[bj][uu] += xv[bj].w * rv.w;
            }
        }
    }

    #pragma unroll
    for (int bj = 0; bj < ROWS_PER_WAVE; ++bj) {
        #pragma unroll
        for (int uu = 0; uu < U_PER_BLOCK; ++uu) {
            float v = acc[bj][uu];
            #pragma unroll
            for (int off = 32; off > 0; off >>= 1)
                v += __shfl_down(v, off, 64);
            if (lane == 0)
                out[(b0 + bj) * UNITS_N + (u0 + uu)] = v + bias[u0 + uu];
        }
    }
}

extern "C" void kernel_launch(void* const* d_in, const int* in_sizes, int n_in,
                              void* d_out, int out_size, void* d_ws, size_t ws_size,
                              hipStream_t stream) {
    const float* x       = (const float*)d_in[0];
    const float* w       = (const float*)d_in[1];
    const float* bias    = (const float*)d_in[2];
    const int*   indices = (const int*)d_in[3];
    float*       out     = (float*)d_out;

    const int L = in_sizes[3] / (UNITS_N * NW_N);
    const size_t Wbytes = (size_t)UNITS_N * D_DIM * sizeof(float);   // 8 MB

    if (ws_size >= Wbytes && d_ws != nullptr) {
        float* W = (float*)d_ws;
        // A: 16384 blocks x 256 thr, one wave per (u,k) bucket.
        EfficientHashedLinear_72043781423546_buildW<<<
            dim3(UNITS_N * NW_N / 4), dim3(256), 0, stream>>>(w, indices, W, L);
        // B: dense skinny GEMM, stream-ordered after A.
        EfficientHashedLinear_72043781423546_gemm<<<
            dim3(UNITS_N / U_PER_BLOCK, B_SPLIT), dim3(THREADS), 0, stream>>>(
            x, W, bias, out);
    } else {
        dim3 grid(UNITS_N / U_PER_BLOCK, B_SPLIT);
        dim3 block(THREADS);
        EfficientHashedLinear_72043781423546_kernel<<<grid, block, 0, stream>>>(
            x, w, bias, indices, out, L);
    }
}

// Round 3
// 80.747 us; speedup vs baseline: 1.1493x; 1.1493x over previous
//
#include <hip/hip_runtime.h>

// B=64, D=2048, UNITS=1024, NW=64; L = in_sizes[3]/(UNITS*NW) (~56).
//
// out[b,u] = sum_i x[b,i] * W[u,i] + bias[u], W[u,i] = w[k] where bucket k of
// unit u contains position i (indices 1-shifted, 0 = pad). Buckets partition
// positions per unit -> LDS scatter builds W[u,:] race-free.
//
// R12: revert R11's two-kernel split (REGRESSED 80.1->92.8: kernel A was
// dispatch-bound at 16K tiny blocks + extra launch gap + global scatter
// write-allocate; lesson: no giant tiny-block grids for 8MB of work).
// Monolithic again, but kill the phase-1 duplication instead:
//   B_SPLIT=1, U_PER_BLOCK=4 -> grid (256,1), 1 block/CU, 16 waves.
//   Each block: ALL 64 batch rows x 4 units. Phase-1 total work halves
//   (index fetch 29.4->14.7 MB, scatter 2M->1M LDS writes, zeroing halves);
//   phase-2 LDS reads/block halve (4 ds_read/step); x logical traffic
//   doubles 64->128MB but x (512KB) is L2-resident -> ~+2us, overlapped.
// Prediction: dur 80.1 -> ~72-76 (kernel ~39 -> ~31). Unchanged => phase 1
// wasn't dominant -> ablate phases next.
//
// Journal: R3 2w/SIMD=48, R4 4w=26, R8 8w=28, R9 U=8/BS=2 dur 80.1,
// R11 split dur 92.8. Timed region carries ~43us ws-poison fill + ~60 tiny
// reset dispatches; kernel-side delta is what we control.

#define B_DIM   64
#define D_DIM   2048
#define D4      (D_DIM / 4)     // 512 float4 per row
#define UNITS_N 1024
#define NW_N    64
#define U_PER_BLOCK 4
#define B_PER_BLOCK B_DIM                           // 64 (B_SPLIT=1)
#define THREADS 1024
#define WAVES   (THREADS / 64)                      // 16
#define PAIRS_PER_WAVE (U_PER_BLOCK * NW_N / WAVES) // 16
#define ROWS_PER_WAVE  (B_PER_BLOCK / WAVES)        // 4
#define STEPS   (D4 / 64)                           // 8

__global__ __launch_bounds__(THREADS)   // NO 2nd arg: 64-VGPR cap + spill (R5)
void EfficientHashedLinear_72043781423546_kernel(
    const float* __restrict__ x,        // (64, 2048)
    const float* __restrict__ w,        // (64,)
    const float* __restrict__ bias,     // (1024,)
    const int*   __restrict__ indices,  // (UNITS, NW, L) int32
    float*       __restrict__ out,      // (64, 1024)
    int L)
{
    __shared__ float rows[U_PER_BLOCK][D_DIM];   // 32 KB
    __shared__ float w_lds[NW_N];

    const int tid  = threadIdx.x;
    const int wave = tid >> 6;          // 0..15
    const int lane = tid & 63;
    const int u0   = blockIdx.x * U_PER_BLOCK;

    // Phase 0: zero rows (float4), stage w.
    {
        float4* r4 = (float4*)rows;
        const float4 z = make_float4(0.f, 0.f, 0.f, 0.f);
        #pragma unroll
        for (int i = tid; i < U_PER_BLOCK * D4; i += THREADS)
            r4[i] = z;
        if (tid < NW_N) w_lds[tid] = w[tid];
    }

    // Phase 1a: index load pass — 16 independent lane-predicated loads/wave,
    // all issued before any use (one batched round trip).
    int idxv[PAIRS_PER_WAVE];
    #pragma unroll
    for (int p = 0; p < PAIRS_PER_WAVE; ++p) {
        const int pair = wave * PAIRS_PER_WAVE + p;   // 0..255
        const int uu   = pair >> 6;                   // 0..3
        const int k    = pair & 63;                   // 0..63
        const int* bp  = indices + ((size_t)(u0 + uu) * NW_N + k) * L;
        idxv[p] = (lane < L) ? bp[lane] : 0;
    }

    __syncthreads();   // rows[] zeroed before scatter

    // Phase 1b: scatter pass (LDS only).
    #pragma unroll
    for (int p = 0; p < PAIRS_PER_WAVE; ++p) {
        const int pair = wave * PAIRS_PER_WAVE + p;
        const int uu   = pair >> 6;
        const int k    = pair & 63;
        if (idxv[p] > 0) rows[uu][idxv[p] - 1] = w_lds[k];
    }
    // Generic tail for L > 64 (not expected with this data; kept for safety).
    if (L > 64) {
        #pragma unroll 1
        for (int p = 0; p < PAIRS_PER_WAVE; ++p) {
            const int pair = wave * PAIRS_PER_WAVE + p;
            const int uu   = pair >> 6;
            const int k    = pair & 63;
            const int* bp  = indices + ((size_t)(u0 + uu) * NW_N + k) * L;
            const float wk = w_lds[k];
            for (int l = 64 + lane; l < L; l += 64) {
                int idx = bp[l];
                if (idx > 0) rows[uu][idx - 1] = wk;
            }
        }
    }
    __syncthreads();

    // Phase 2: wave owns 4 batch rows x 4 units. Each x float4 feeds 4 units;
    // each LDS row read feeds 4 batch rows.
    const int b0 = wave * ROWS_PER_WAVE;
    const float4* x4 = (const float4*)x;

    float acc[ROWS_PER_WAVE][U_PER_BLOCK];
    #pragma unroll
    for (int bj = 0; bj < ROWS_PER_WAVE; ++bj)
        #pragma unroll
        for (int uu = 0; uu < U_PER_BLOCK; ++uu)
            acc[bj][uu] = 0.0f;

    #pragma unroll 1   // keep live set small; big unrolls spill (R2/R5)
    for (int step = 0; step < STEPS; ++step) {
        const int i4 = step * 64 + lane;          // 0..511
        float4 xv[ROWS_PER_WAVE];
        #pragma unroll
        for (int bj = 0; bj < ROWS_PER_WAVE; ++bj)
            xv[bj] = x4[(b0 + bj) * D4 + i4];     // 4 loads, one round trip
        #pragma unroll
        for (int uu = 0; uu < U_PER_BLOCK; ++uu) {
            const float4 rv = ((const float4*)rows[uu])[i4];   // ds_read_b128
            #pragma unroll
            for (int bj = 0; bj < ROWS_PER_WAVE; ++bj) {
                acc[bj][uu] += xv[bj].x * rv.x;
                acc[bj][uu] += xv[bj].y * rv.y;
                acc[bj][uu] += xv[bj].z * rv.z;
                acc[bj][uu] += xv[bj].w * rv.w;
            }
        }
    }

    // Phase 3: butterfly reduce, add bias, store (16 outputs/wave).
    #pragma unroll
    for (int bj = 0; bj < ROWS_PER_WAVE; ++bj) {
        #pragma unroll
        for (int uu = 0; uu < U_PER_BLOCK; ++uu) {
            float v = acc[bj][uu];
            #pragma unroll
            for (int off = 32; off > 0; off >>= 1)
                v += __shfl_down(v, off, 64);
            if (lane == 0)
                out[(b0 + bj) * UNITS_N + (u0 + uu)] = v + bias[u0 + uu];
        }
    }
}

extern "C" void kernel_launch(void* const* d_in, const int* in_sizes, int n_in,
                              void* d_out, int out_size, void* d_ws, size_t ws_size,
                              hipStream_t stream) {
    const float* x       = (const float*)d_in[0];
    const float* w       = (const float*)d_in[1];
    const float* bias    = (const float*)d_in[2];
    const int*   indices = (const int*)d_in[3];
    float*       out     = (float*)d_out;

    const int L = in_sizes[3] / (UNITS_N * NW_N);

    dim3 grid(UNITS_N / U_PER_BLOCK);   // 256 blocks = 1/CU
    dim3 block(THREADS);                // 1024 threads = 16 waves
    EfficientHashedLinear_72043781423546_kernel<<<grid, block, 0, stream>>>(
        x, w, bias, indices, out, L);
}